// Round 5
// baseline (512.588 us; speedup 1.0000x reference)
//
#include <hip/hip_runtime.h>

#define D 128
#define EPSV 1e-5f

typedef __attribute__((ext_vector_type(8))) __bf16 bf16x8;
typedef __attribute__((ext_vector_type(4))) float f32x4;

__device__ __forceinline__ ushort f2bf(float x) {
  unsigned u = __float_as_uint(x);
  u += 0x7fffu + ((u >> 16) & 1u);
  return (ushort)(u >> 16);
}
__device__ __forceinline__ unsigned pk2(float a, float b) {
  return (unsigned)f2bf(a) | ((unsigned)f2bf(b) << 16);
}
__device__ __forceinline__ float bf2f(ushort u) {
  return __uint_as_float((unsigned)u << 16);
}

// ---------------------------------------------------------------------------
// Wc1 (256x128 f32) -> WT1 (128x256 bf16 transposed); Wc2 -> WT2 (128x128).
__global__ void k_cvt(const float* __restrict__ Wc1, const float* __restrict__ Wc2,
                      ushort* __restrict__ WT1, ushort* __restrict__ WT2) {
  int i = blockIdx.x * 256 + threadIdx.x;
  if (i < 128 * 256) {
    int n = i >> 8, k = i & 255;
    WT1[i] = f2bf(Wc1[k * 128 + n]);
  } else {
    int j = i - 128 * 256;
    if (j < 128 * 128) {
      int n = j >> 7, k = j & 127;
      WT2[j] = f2bf(Wc2[k * 128 + n]);
    }
  }
}

// ---------------------------------------------------------------------------
// CSR build: counting sort of edges by wi.
__global__ void k_hist(const int* __restrict__ wi, int* __restrict__ hist, int E) {
  int i = blockIdx.x * 256 + threadIdx.x;
  if (i < E) atomicAdd(&hist[wi[i]], 1);
}

__global__ void k_scan1(const int* __restrict__ hist, int* __restrict__ bsum, int Nt) {
  __shared__ int sd[256];
  int t = threadIdx.x, i = blockIdx.x * 256 + t;
  sd[t] = (i < Nt) ? hist[i] : 0;
  __syncthreads();
  for (int off = 128; off > 0; off >>= 1) {
    if (t < off) sd[t] += sd[t + off];
    __syncthreads();
  }
  if (t == 0) bsum[blockIdx.x] = sd[0];
}

__global__ void k_scan2(const int* __restrict__ bsum, int* __restrict__ bpre, int nc) {
  __shared__ int sd[256];
  int t = threadIdx.x;
  int v = (t < nc) ? bsum[t] : 0;
  sd[t] = v;
  __syncthreads();
  for (int off = 1; off < 256; off <<= 1) {
    int x = (t >= off) ? sd[t - off] : 0;
    __syncthreads();
    sd[t] += x;
    __syncthreads();
  }
  if (t < nc) bpre[t] = sd[t] - v;  // exclusive
}

__global__ void k_scan3(const int* __restrict__ hist, const int* __restrict__ bpre,
                        int* __restrict__ cursor, int Nt) {
  __shared__ int sd[256];
  int t = threadIdx.x, i = blockIdx.x * 256 + t;
  int v = (i < Nt) ? hist[i] : 0;
  sd[t] = v;
  __syncthreads();
  for (int off = 1; off < 256; off <<= 1) {
    int x = (t >= off) ? sd[t - off] : 0;
    __syncthreads();
    sd[t] += x;
    __syncthreads();
  }
  if (i < Nt) cursor[i] = bpre[blockIdx.x] + sd[t] - v;  // exclusive offsets
}

__global__ void k_order(const int* __restrict__ wi, int* __restrict__ cursor,
                        int* __restrict__ order, int E) {
  int i = blockIdx.x * 256 + threadIdx.x;
  if (i < E) {
    int p = atomicAdd(&cursor[wi[i]], 1);
    order[p] = i;
  }
}

// ---------------------------------------------------------------------------
// k_edge (v3-verified structure + sorted-edge segmented-reduce scatter):
// 128 edges/block, 4 waves (2x2), wave tile 64x64; W double-buffered via
// global_load_lds; relpose + Y in Ybuf (stride 136). Epilogue: acc2 -> LDS
// bf16 (swizzled), run detection over sorted wl, one atomic per (run, col).
__global__ __launch_bounds__(256, 3) void k_edge(
    const float* __restrict__ cfeat,
    const float* __restrict__ cpose, const float* __restrict__ tpose,
    const float* __restrict__ Wrp, const float* __restrict__ brp,
    const float* __restrict__ gc1, const float* __restrict__ bc1,
    const ushort* __restrict__ WT1, const ushort* __restrict__ WT2,
    const int* __restrict__ hi, const int* __restrict__ wi,
    const int* __restrict__ order,
    float* __restrict__ acc, int E) {
  __shared__ ushort Wbuf[2][4096];      // 2 x 8KB: one K=32 chunk, 128 cols
  __shared__ ushort Ybuf[128 * 136];    // relpose X2 / Y / acc2-bf16 staging
  __shared__ float gnbuf[2][128][2];
  __shared__ int wl[128];
  __shared__ int runstart[129];
  __shared__ int nruns_s;
  __shared__ unsigned long long mask0_s;

  const int t = threadIdx.x;
  const int lane = t & 63;
  const int wv = t >> 6;
  const int wm = wv >> 1, wn = wv & 1;
  const int s = lane & 15, g = lane >> 4;
  const int e0 = blockIdx.x * 128;

  auto eidOf = [&](int p) {
    p = min(p, E - 1);
    return order ? order[p] : p;
  };

  auto stage = [&](int c, int nb) {
    const ushort* Wt = (c < 8) ? WT1 : WT2;
    const int koff = (c < 8 ? c : c - 8) * 32;
    const int krow = (c < 8) ? 256 : 128;
    const int col = t & 127, g0 = t >> 7;
#pragma unroll
    for (int v = 0; v < 2; ++v) {
      const int gg = g0 + v * 2;
      const ushort* src = Wt + (size_t)col * krow + koff + gg * 8;
      ushort* dst = &Wbuf[nb][(gg * 128 + col) * 8];
      __builtin_amdgcn_global_load_lds(
          (const __attribute__((address_space(1))) void*)src,
          (__attribute__((address_space(3))) void*)dst, 16, 0, 0);
    }
  };

  stage(0, 0);
  if (t < 128) wl[t] = wi[eidOf(e0 + t)];

  int hl[4];
#pragma unroll
  for (int m = 0; m < 4; ++m)
    hl[m] = hi[eidOf(e0 + wm * 64 + m * 16 + s)];

  // relpose: edge e = t>>1, col half (t&1)*64 -> Ybuf (bf16, stride 136)
  {
    const int e = t >> 1;
    const int jh = (t & 1) * 64;
    const int ge = eidOf(e0 + e);
    const int h = hi[ge], w = wi[ge];
    float4 cp = *(const float4*)(cpose + (size_t)h * 4);
    float4 tp = *(const float4*)(tpose + (size_t)w * 4);
    const float d0 = cp.x - tp.x, d1 = cp.y - tp.y;
    const float d2 = cp.z - tp.z, d3 = cp.w - tp.w;
#pragma unroll
    for (int q = 0; q < 16; ++q) {
      const int j = jh + q * 4;
      float4 b  = *(const float4*)(brp + j);
      float4 w0 = *(const float4*)(Wrp + j);
      float4 w1 = *(const float4*)(Wrp + D + j);
      float4 w2 = *(const float4*)(Wrp + 2 * D + j);
      float4 w3 = *(const float4*)(Wrp + 3 * D + j);
      float r0 = fmaxf(b.x + d0 * w0.x + d1 * w1.x + d2 * w2.x + d3 * w3.x, 0.f);
      float r1 = fmaxf(b.y + d0 * w0.y + d1 * w1.y + d2 * w2.y + d3 * w3.y, 0.f);
      float r2 = fmaxf(b.z + d0 * w0.z + d1 * w1.z + d2 * w2.z + d3 * w3.z, 0.f);
      float r3 = fmaxf(b.w + d0 * w0.w + d1 * w1.w + d2 * w2.w + d3 * w3.w, 0.f);
      *(uint2*)&Ybuf[e * 136 + j] = make_uint2(pk2(r0, r1), pk2(r2, r3));
    }
  }
  __syncthreads();  // B1: Wbuf[0], Ybuf (relpose), wl ready

  // ---- GEMM1: K=256 (chunks 0..3 cfeat-from-global, 4..7 relpose-from-LDS)
  f32x4 acc1[4][4];
#pragma unroll
  for (int m = 0; m < 4; ++m)
#pragma unroll
    for (int n = 0; n < 4; ++n) acc1[m][n] = (f32x4){0.f, 0.f, 0.f, 0.f};

  for (int kc = 0; kc < 8; ++kc) {
    const int nb = kc & 1;
    stage(kc + 1, nb ^ 1);
    bf16x8 a[4];
    if (kc < 4) {
#pragma unroll
      for (int m = 0; m < 4; ++m) {
        const float* src = cfeat + (size_t)hl[m] * D + kc * 32 + g * 8;
        float4 f0 = *(const float4*)src;
        float4 f1 = *(const float4*)(src + 4);
        union { uint4 u; bf16x8 v; } cv;
        cv.u.x = pk2(f0.x, f0.y); cv.u.y = pk2(f0.z, f0.w);
        cv.u.z = pk2(f1.x, f1.y); cv.u.w = pk2(f1.z, f1.w);
        a[m] = cv.v;
      }
    } else {
#pragma unroll
      for (int m = 0; m < 4; ++m)
        a[m] = *(const bf16x8*)
            &Ybuf[(wm * 64 + m * 16 + s) * 136 + (kc - 4) * 32 + g * 8];
    }
#pragma unroll
    for (int n = 0; n < 4; ++n) {
      bf16x8 b = *(const bf16x8*)
          &Wbuf[nb][(g * 128 + wn * 64 + n * 16 + s) * 8];
#pragma unroll
      for (int m = 0; m < 4; ++m)
        acc1[m][n] =
            __builtin_amdgcn_mfma_f32_16x16x32_bf16(a[m], b, acc1[m][n], 0, 0, 0);
    }
    __syncthreads();
  }

  // ---- GN stats ----
#pragma unroll
  for (int m = 0; m < 4; ++m) {
#pragma unroll
    for (int reg = 0; reg < 4; ++reg) {
      float p1 = acc1[m][0][reg] + acc1[m][1][reg] + acc1[m][2][reg] +
                 acc1[m][3][reg];
      float p2 = acc1[m][0][reg] * acc1[m][0][reg] +
                 acc1[m][1][reg] * acc1[m][1][reg] +
                 acc1[m][2][reg] * acc1[m][2][reg] +
                 acc1[m][3][reg] * acc1[m][3][reg];
#pragma unroll
      for (int msk = 1; msk < 16; msk <<= 1) {
        p1 += __shfl_xor(p1, msk, 64);
        p2 += __shfl_xor(p2, msk, 64);
      }
      if (s == 0) {
        const int row = wm * 64 + m * 16 + g * 4 + reg;
        *(float2*)&gnbuf[wn][row][0] = make_float2(p1, p2);
      }
    }
  }
  __syncthreads();  // B2: gnbuf ready; all GEMM1 LDS reads complete

  // ---- normalize + relu -> Ybuf (Y, stride 136) ----
  {
    float gcl[4], bcl[4];
#pragma unroll
    for (int n = 0; n < 4; ++n) {
      gcl[n] = gc1[wn * 64 + n * 16 + s];
      bcl[n] = bc1[wn * 64 + n * 16 + s];
    }
#pragma unroll
    for (int m = 0; m < 4; ++m) {
#pragma unroll
      for (int reg = 0; reg < 4; ++reg) {
        const int row = wm * 64 + m * 16 + g * 4 + reg;
        float2 q0 = *(const float2*)&gnbuf[0][row][0];
        float2 q1 = *(const float2*)&gnbuf[1][row][0];
        const float mean = (q0.x + q1.x) * (1.f / 128.f);
        const float var = (q0.y + q1.y) * (1.f / 128.f) - mean * mean;
        const float rstd = rsqrtf(var + EPSV);
#pragma unroll
        for (int n = 0; n < 4; ++n) {
          float y = (acc1[m][n][reg] - mean) * rstd * gcl[n] + bcl[n];
          Ybuf[row * 136 + wn * 64 + n * 16 + s] = f2bf(fmaxf(y, 0.f));
        }
      }
    }
  }
  __syncthreads();  // B3: Y ready

  // ---- GEMM2: K=128 (W chunks 8..11), A = Ybuf ----
  f32x4 acc2[4][4];
#pragma unroll
  for (int m = 0; m < 4; ++m)
#pragma unroll
    for (int n = 0; n < 4; ++n) acc2[m][n] = (f32x4){0.f, 0.f, 0.f, 0.f};

  for (int kc = 0; kc < 4; ++kc) {
    const int c = 8 + kc;
    const int nb = c & 1;
    if (c < 11) stage(c + 1, nb ^ 1);
    bf16x8 a[4];
#pragma unroll
    for (int m = 0; m < 4; ++m)
      a[m] = *(const bf16x8*)
          &Ybuf[(wm * 64 + m * 16 + s) * 136 + kc * 32 + g * 8];
#pragma unroll
    for (int n = 0; n < 4; ++n) {
      bf16x8 b = *(const bf16x8*)
          &Wbuf[nb][(g * 128 + wn * 64 + n * 16 + s) * 8];
#pragma unroll
      for (int m = 0; m < 4; ++m)
        acc2[m][n] =
            __builtin_amdgcn_mfma_f32_16x16x32_bf16(a[m], b, acc2[m][n], 0, 0, 0);
    }
    if (kc < 3) __syncthreads();
  }

  // ---- epilogue: segmented reduction over sorted targets ----
  // run detection on wl (stable since B1)
  bool head = false;
  if (t < 128) head = (t == 0) || (wl[t] != wl[t - 1]);
  unsigned long long bm = __ballot(head);
  if (t == 0) mask0_s = bm;
  __syncthreads();  // E1: mask0_s visible; all GEMM2 Ybuf reads complete

  if (t < 128) {
    const int base = (t >= 64) ? __popcll(mask0_s) : 0;
    const int rank = base + __popcll(bm & ((1ULL << lane) - 1));
    if (head) runstart[rank] = t;
    if (t == 64) nruns_s = __popcll(mask0_s) + __popcll(bm);
  }
  if (t == 127 && false) {}  // (no-op; nruns written by t==64 above)

  // acc2 -> Ybuf as bf16 [128][128], XOR-swizzled; invalid rows -> 0
#pragma unroll
  for (int m = 0; m < 4; ++m) {
#pragma unroll
    for (int reg = 0; reg < 4; ++reg) {
      const int row = wm * 64 + m * 16 + g * 4 + reg;
      const bool vld = (e0 + row) < E;
      const int sw = (row & 7) << 3;
#pragma unroll
      for (int n = 0; n < 4; ++n) {
        const int col = wn * 64 + n * 16 + s;
        Ybuf[row * 128 + (col ^ sw)] = vld ? f2bf(acc2[m][n][reg]) : (ushort)0;
      }
    }
  }
  __syncthreads();  // E2: runstart, nruns_s, staged acc2 all visible

  {
    const int nr = nruns_s;
    for (int task = t; task < (nr << 7); task += 256) {
      const int run = task >> 7, col = task & 127;
      const int r0 = runstart[run];
      const int r1 = (run + 1 < nr) ? runstart[run + 1] : 128;
      const int w = wl[r0];
      float sum = 0.f;
      for (int r = r0; r < r1; ++r)
        sum += bf2f(Ybuf[r * 128 + (col ^ ((r & 7) << 3))]);
      unsafeAtomicAdd(acc + (size_t)w * D + col, sum);
    }
  }
}

// ---------------------------------------------------------------------------
__device__ __forceinline__ void reduce16(float& a, float& b) {
#pragma unroll
  for (int w = 1; w < 16; w <<= 1) {
    a += __shfl_xor(a, w, 64);
    b += __shfl_xor(b, w, 64);
  }
}

// ---------------------------------------------------------------------------
// k_input: 64 rows/block, 4 rows/thread.
__global__ __launch_bounds__(256, 2) void k_input(
    const float* __restrict__ tfeat, const float* __restrict__ Wi,
    float* __restrict__ acc, int N) {
  __shared__ float Wbuf[64][132];
  __shared__ float xt[64][132];
  const int t = threadIdx.x;
  const int r = t >> 4, s = t & 15, j0 = s * 8;
  const int row0 = blockIdx.x * 64;

  for (int idx = t; idx < 64 * 32; idx += 256) {
    int rr = idx >> 5, c4 = idx & 31;
    int grow = row0 + rr;
    float4 v = make_float4(0.f, 0.f, 0.f, 0.f);
    if (grow < N) v = *(const float4*)(tfeat + (size_t)grow * D + c4 * 4);
    *(float4*)&xt[rr][c4 * 4] = v;
  }

  float a[4][8] = {};
  for (int kc = 0; kc < 2; ++kc) {
    __syncthreads();
    for (int idx = t; idx < 64 * 32; idx += 256) {
      int kk = idx >> 5, c4 = idx & 31;
      *(float4*)&Wbuf[kk][c4 * 4] =
          *(const float4*)(Wi + (size_t)(kc * 64 + kk) * D + c4 * 4);
    }
    __syncthreads();
#pragma unroll 4
    for (int kk = 0; kk < 64; ++kk) {
      float4 w0 = *(const float4*)&Wbuf[kk][j0];
      float4 w1 = *(const float4*)&Wbuf[kk][j0 + 4];
#pragma unroll
      for (int i = 0; i < 4; ++i) {
        float xv = xt[r + 16 * i][kc * 64 + kk];
        a[i][0] += xv * w0.x; a[i][1] += xv * w0.y;
        a[i][2] += xv * w0.z; a[i][3] += xv * w0.w;
        a[i][4] += xv * w1.x; a[i][5] += xv * w1.y;
        a[i][6] += xv * w1.z; a[i][7] += xv * w1.w;
      }
    }
  }
#pragma unroll
  for (int i = 0; i < 4; ++i) {
    int row = row0 + r + 16 * i;
    if (row < N) {
      *(float4*)(acc + (size_t)row * D + j0) =
          make_float4(a[i][0], a[i][1], a[i][2], a[i][3]);
      *(float4*)(acc + (size_t)row * D + j0 + 4) =
          make_float4(a[i][4], a[i][5], a[i][6], a[i][7]);
    }
  }
}

// ---------------------------------------------------------------------------
// k_node: 64 rows/block, 4 rows/thread; xt reused between stages.
__global__ __launch_bounds__(256, 2) void k_node(
    const float* __restrict__ tfeat,
    const float* __restrict__ gn, const float* __restrict__ bn,
    const float* __restrict__ Wm1, const float* __restrict__ gm1,
    const float* __restrict__ bm1,
    const float* __restrict__ Wm2, const float* __restrict__ gm2,
    const float* __restrict__ bm2,
    float* __restrict__ acc, int N) {
  __shared__ float Wbuf[64][132];
  __shared__ float xt[64][132];
  const int t = threadIdx.x;
  const int r = t >> 4, s = t & 15, j0 = s * 8;
  const int row0 = blockIdx.x * 64;

  auto stageW = [&](const float* W, int kc) {
    for (int idx = t; idx < 64 * 32; idx += 256) {
      int kk = idx >> 5, c4 = idx & 31;
      *(float4*)&Wbuf[kk][c4 * 4] =
          *(const float4*)(W + (size_t)(kc * 64 + kk) * D + c4 * 4);
    }
  };
  auto gemm = [&](float (&a)[4][8], int kc) {
#pragma unroll 4
    for (int kk = 0; kk < 64; ++kk) {
      float4 w0 = *(const float4*)&Wbuf[kk][j0];
      float4 w1 = *(const float4*)&Wbuf[kk][j0 + 4];
#pragma unroll
      for (int i = 0; i < 4; ++i) {
        float xv = xt[r + 16 * i][kc * 64 + kk];
        a[i][0] += xv * w0.x; a[i][1] += xv * w0.y;
        a[i][2] += xv * w0.z; a[i][3] += xv * w0.w;
        a[i][4] += xv * w1.x; a[i][5] += xv * w1.y;
        a[i][6] += xv * w1.z; a[i][7] += xv * w1.w;
      }
    }
  };

  {
    float gv[8], bv[8];
#pragma unroll
    for (int m = 0; m < 8; ++m) { gv[m] = gn[j0 + m]; bv[m] = bn[j0 + m]; }
#pragma unroll
    for (int i = 0; i < 4; ++i) {
      int row = row0 + r + 16 * i;
      float v[8] = {};
      if (row < N) {
        float4 v0 = *(const float4*)(acc + (size_t)row * D + j0);
        float4 v1 = *(const float4*)(acc + (size_t)row * D + j0 + 4);
        v[0] = v0.x; v[1] = v0.y; v[2] = v0.z; v[3] = v0.w;
        v[4] = v1.x; v[5] = v1.y; v[6] = v1.z; v[7] = v1.w;
      }
      float s1 = 0.f, s2 = 0.f;
#pragma unroll
      for (int m = 0; m < 8; ++m) { s1 += v[m]; s2 += v[m] * v[m]; }
      reduce16(s1, s2);
      float mean = s1 * (1.f / 128.f);
      float var = s2 * (1.f / 128.f) - mean * mean;
      float rstd = rsqrtf(var + EPSV);
#pragma unroll
      for (int m = 0; m < 8; ++m)
        xt[r + 16 * i][j0 + m] = fmaxf((v[m] - mean) * rstd * gv[m] + bv[m], 0.f);
    }
  }

  float a[4][8] = {};
  for (int kc = 0; kc < 2; ++kc) {
    __syncthreads();
    stageW(Wm1, kc);
    __syncthreads();
    gemm(a, kc);
  }
  __syncthreads();
  {
    float gv[8], bv[8];
#pragma unroll
    for (int m = 0; m < 8; ++m) { gv[m] = gm1[j0 + m]; bv[m] = bm1[j0 + m]; }
#pragma unroll
    for (int i = 0; i < 4; ++i) {
      float s1 = 0.f, s2 = 0.f;
#pragma unroll
      for (int m = 0; m < 8; ++m) { s1 += a[i][m]; s2 += a[i][m] * a[i][m]; }
      reduce16(s1, s2);
      float mean = s1 * (1.f / 128.f);
      float var = s2 * (1.f / 128.f) - mean * mean;
      float rstd = rsqrtf(var + EPSV);
#pragma unroll
      for (int m = 0; m < 8; ++m)
        xt[r + 16 * i][j0 + m] =
            fmaxf((a[i][m] - mean) * rstd * gv[m] + bv[m], 0.f);
    }
  }

  float a2[4][8] = {};
  for (int kc = 0; kc < 2; ++kc) {
    __syncthreads();
    stageW(Wm2, kc);
    __syncthreads();
    gemm(a2, kc);
  }
  {
    float gv[8], bv[8];
#pragma unroll
    for (int m = 0; m < 8; ++m) { gv[m] = gm2[j0 + m]; bv[m] = bm2[j0 + m]; }
#pragma unroll
    for (int i = 0; i < 4; ++i) {
      int row = row0 + r + 16 * i;
      float s1 = 0.f, s2 = 0.f;
#pragma unroll
      for (int m = 0; m < 8; ++m) { s1 += a2[i][m]; s2 += a2[i][m] * a2[i][m]; }
      reduce16(s1, s2);
      float mean = s1 * (1.f / 128.f);
      float var = s2 * (1.f / 128.f) - mean * mean;
      float rstd = rsqrtf(var + EPSV);
      if (row < N) {
        float o[8];
#pragma unroll
        for (int m = 0; m < 8; ++m) {
          float x = (a2[i][m] - mean) * rstd * gv[m] + bv[m];
          o[m] = fmaxf(x + tfeat[(size_t)row * D + j0 + m], 0.f);
        }
        *(float4*)(acc + (size_t)row * D + j0) =
            make_float4(o[0], o[1], o[2], o[3]);
        *(float4*)(acc + (size_t)row * D + j0 + 4) =
            make_float4(o[4], o[5], o[6], o[7]);
      }
    }
  }
}

// ---------------------------------------------------------------------------
extern "C" void kernel_launch(void* const* d_in, const int* in_sizes, int n_in,
                              void* d_out, int out_size, void* d_ws,
                              size_t ws_size, hipStream_t stream) {
  const float* cfeat = (const float*)d_in[0];
  const float* tfeat = (const float*)d_in[1];
  const float* cpose = (const float*)d_in[2];
  const float* tpose = (const float*)d_in[3];
  const float* Wi    = (const float*)d_in[4];
  const float* Wrp   = (const float*)d_in[5];
  const float* brp   = (const float*)d_in[6];
  const float* Wc1   = (const float*)d_in[7];
  const float* gc1   = (const float*)d_in[8];
  const float* bc1   = (const float*)d_in[9];
  const float* Wc2   = (const float*)d_in[10];
  const float* gn    = (const float*)d_in[11];
  const float* bn    = (const float*)d_in[12];
  const float* Wm1   = (const float*)d_in[13];
  const float* gm1   = (const float*)d_in[14];
  const float* bm1   = (const float*)d_in[15];
  const float* Wm2   = (const float*)d_in[16];
  const float* gm2   = (const float*)d_in[17];
  const float* bm2   = (const float*)d_in[18];
  const int* hi      = (const int*)d_in[19];
  const int* wi      = (const int*)d_in[20];

  const int N = in_sizes[1] / D;   // 40000 targets
  const int E = in_sizes[19];      // 640000 edges
  float* out = (float*)d_out;      // f32 accumulator == output

  // workspace layout
  uint8_t* ws = (uint8_t*)d_ws;
  ushort* WT1 = (ushort*)ws;                       // 65536 B
  ushort* WT2 = (ushort*)(ws + 65536);             // 32768 B
  size_t off = 98304;
  int* hist   = (int*)(ws + off); off += (size_t)N * 4;
  int* cursor = (int*)(ws + off); off += (size_t)N * 4;
  int* bsum   = (int*)(ws + off); off += 1024;
  int* bpre   = (int*)(ws + off); off += 1024;
  int* order  = (int*)(ws + off); off += (size_t)E * 4;

  const int nchunks = (N + 255) / 256;
  const bool sorted = (ws_size >= off) && (nchunks <= 256);

  const int nbN = (N + 63) / 64;
  const int nbE = (E + 127) / 128;
  const int nbEthr = (E + 255) / 256;

  if (sorted) {
    hipMemsetAsync(hist, 0, (size_t)N * 4, stream);
    k_hist<<<nbEthr, 256, 0, stream>>>(wi, hist, E);
    k_scan1<<<nchunks, 256, 0, stream>>>(hist, bsum, N);
    k_scan2<<<1, 256, 0, stream>>>(bsum, bpre, nchunks);
    k_scan3<<<nchunks, 256, 0, stream>>>(hist, bpre, cursor, N);
    k_order<<<nbEthr, 256, 0, stream>>>(wi, cursor, order, E);
  }

  k_cvt<<<192, 256, 0, stream>>>(Wc1, Wc2, WT1, WT2);
  k_input<<<nbN, 256, 0, stream>>>(tfeat, Wi, out, N);
  k_edge<<<nbE, 256, 0, stream>>>(cfeat, cpose, tpose, Wrp, brp, gc1, bc1,
                                  WT1, WT2, hi, wi, sorted ? order : nullptr,
                                  out, E);
  k_node<<<nbN, 256, 0, stream>>>(tfeat, gn, bn, Wm1, gm1, bm1, Wm2, gm2, bm2,
                                  out, N);
}

// Round 6
// 444.842 us; speedup vs baseline: 1.1523x; 1.1523x over previous
//
#include <hip/hip_runtime.h>

#define D 128
#define EPSV 1e-5f

typedef __attribute__((ext_vector_type(8))) __bf16 bf16x8;
typedef __attribute__((ext_vector_type(4))) float f32x4;

__device__ __forceinline__ ushort f2bf(float x) {
  unsigned u = __float_as_uint(x);
  u += 0x7fffu + ((u >> 16) & 1u);
  return (ushort)(u >> 16);
}
// single-instruction packed f32x2 -> bf16x2 (RNE), lo -> [15:0], hi -> [31:16]
__device__ __forceinline__ unsigned cvtpk(float lo, float hi) {
  unsigned r;
  asm("v_cvt_pk_bf16_f32 %0, %1, %2" : "=v"(r) : "v"(lo), "v"(hi));
  return r;
}
// XOR-swizzled [128][128] ushort tile index (16B-granule bijection per 8 rows)
__device__ __forceinline__ int yidx(int row, int col) {
  return row * 128 + (col ^ ((row & 7) << 3));
}

// ---------------------------------------------------------------------------
// Wc1 (256x128 f32) -> WT1 (128x256 bf16 transposed); Wc2 -> WT2 (128x128).
__global__ void k_cvt(const float* __restrict__ Wc1, const float* __restrict__ Wc2,
                      ushort* __restrict__ WT1, ushort* __restrict__ WT2) {
  int i = blockIdx.x * 256 + threadIdx.x;
  if (i < 128 * 256) {
    int n = i >> 8, k = i & 255;
    WT1[i] = f2bf(Wc1[k * 128 + n]);
  } else {
    int j = i - 128 * 256;
    if (j < 128 * 128) {
      int n = j >> 7, k = j & 127;
      WT2[j] = f2bf(Wc2[k * 128 + n]);
    }
  }
}

// ---------------------------------------------------------------------------
// k_edge v6: R3-verified structure; 128 edges/block, 4 waves (2x2), 64x64/wave.
// Changes vs R3: v_cvt_pk_bf16_f32 conversions, swizzled 32KB Ybuf -> 50.5KB
// LDS -> 3 blocks/CU.
__global__ __launch_bounds__(256, 3) void k_edge(
    const float* __restrict__ cfeat,
    const float* __restrict__ cpose, const float* __restrict__ tpose,
    const float* __restrict__ Wrp, const float* __restrict__ brp,
    const float* __restrict__ gc1, const float* __restrict__ bc1,
    const ushort* __restrict__ WT1, const ushort* __restrict__ WT2,
    const int* __restrict__ hi, const int* __restrict__ wi,
    float* __restrict__ acc, int E) {
  __shared__ ushort Wbuf[2][4096];   // 2 x 8KB: one K=32 chunk of W^T, 128 cols
  __shared__ ushort Ybuf[128 * 128]; // relpose X2 / Y, XOR-swizzled
  __shared__ float gnbuf[2][128][2];
  __shared__ int wl[128];

  const int t = threadIdx.x;
  const int lane = t & 63;
  const int wv = t >> 6;
  const int wm = wv >> 1, wn = wv & 1;
  const int s = lane & 15, g = lane >> 4;
  const int e0 = blockIdx.x * 128;

  auto stage = [&](int c, int nb) {
    const ushort* Wt = (c < 8) ? WT1 : WT2;
    const int koff = (c < 8 ? c : c - 8) * 32;
    const int krow = (c < 8) ? 256 : 128;
    const int col = t & 127, g0 = t >> 7;
#pragma unroll
    for (int v = 0; v < 2; ++v) {
      const int gg = g0 + v * 2;
      const ushort* src = Wt + (size_t)col * krow + koff + gg * 8;
      ushort* dst = &Wbuf[nb][(gg * 128 + col) * 8];
      __builtin_amdgcn_global_load_lds(
          (const __attribute__((address_space(1))) void*)src,
          (__attribute__((address_space(3))) void*)dst, 16, 0, 0);
    }
  };

  stage(0, 0);
  if (t < 128) wl[t] = wi[min(e0 + t, E - 1)];

  int hl[4];
#pragma unroll
  for (int m = 0; m < 4; ++m)
    hl[m] = hi[min(e0 + wm * 64 + m * 16 + s, E - 1)];

  // relpose: edge e = t>>1, col half (t&1)*64 -> Ybuf (bf16, swizzled)
  {
    const int e = t >> 1;
    const int jh = (t & 1) * 64;
    const int ge = min(e0 + e, E - 1);
    const int h = hi[ge], w = wi[ge];
    float4 cp = *(const float4*)(cpose + (size_t)h * 4);
    float4 tp = *(const float4*)(tpose + (size_t)w * 4);
    const float d0 = cp.x - tp.x, d1 = cp.y - tp.y;
    const float d2 = cp.z - tp.z, d3 = cp.w - tp.w;
#pragma unroll
    for (int q = 0; q < 16; ++q) {
      const int j = jh + q * 4;
      float4 b  = *(const float4*)(brp + j);
      float4 w0 = *(const float4*)(Wrp + j);
      float4 w1 = *(const float4*)(Wrp + D + j);
      float4 w2 = *(const float4*)(Wrp + 2 * D + j);
      float4 w3 = *(const float4*)(Wrp + 3 * D + j);
      float r0 = fmaxf(b.x + d0 * w0.x + d1 * w1.x + d2 * w2.x + d3 * w3.x, 0.f);
      float r1 = fmaxf(b.y + d0 * w0.y + d1 * w1.y + d2 * w2.y + d3 * w3.y, 0.f);
      float r2 = fmaxf(b.z + d0 * w0.z + d1 * w1.z + d2 * w2.z + d3 * w3.z, 0.f);
      float r3 = fmaxf(b.w + d0 * w0.w + d1 * w1.w + d2 * w2.w + d3 * w3.w, 0.f);
      *(uint2*)&Ybuf[yidx(e, j)] = make_uint2(cvtpk(r0, r1), cvtpk(r2, r3));
    }
  }
  __syncthreads();  // B1: Wbuf[0], Ybuf (relpose), wl ready

  // ---- GEMM1: K=256 (chunks 0..3 cfeat-from-global, 4..7 relpose-from-LDS)
  f32x4 acc1[4][4];
#pragma unroll
  for (int m = 0; m < 4; ++m)
#pragma unroll
    for (int n = 0; n < 4; ++n) acc1[m][n] = (f32x4){0.f, 0.f, 0.f, 0.f};

  for (int kc = 0; kc < 8; ++kc) {
    const int nb = kc & 1;
    stage(kc + 1, nb ^ 1);
    bf16x8 a[4];
    if (kc < 4) {
#pragma unroll
      for (int m = 0; m < 4; ++m) {
        const float* src = cfeat + (size_t)hl[m] * D + kc * 32 + g * 8;
        float4 f0 = *(const float4*)src;
        float4 f1 = *(const float4*)(src + 4);
        union { uint4 u; bf16x8 v; } cv;
        cv.u.x = cvtpk(f0.x, f0.y); cv.u.y = cvtpk(f0.z, f0.w);
        cv.u.z = cvtpk(f1.x, f1.y); cv.u.w = cvtpk(f1.z, f1.w);
        a[m] = cv.v;
      }
    } else {
#pragma unroll
      for (int m = 0; m < 4; ++m)
        a[m] = *(const bf16x8*)
            &Ybuf[yidx(wm * 64 + m * 16 + s, (kc - 4) * 32 + g * 8)];
    }
#pragma unroll
    for (int n = 0; n < 4; ++n) {
      bf16x8 b = *(const bf16x8*)
          &Wbuf[nb][(g * 128 + wn * 64 + n * 16 + s) * 8];
#pragma unroll
      for (int m = 0; m < 4; ++m)
        acc1[m][n] =
            __builtin_amdgcn_mfma_f32_16x16x32_bf16(a[m], b, acc1[m][n], 0, 0, 0);
    }
    __syncthreads();
  }

  // ---- GN stats ----
#pragma unroll
  for (int m = 0; m < 4; ++m) {
#pragma unroll
    for (int reg = 0; reg < 4; ++reg) {
      float p1 = acc1[m][0][reg] + acc1[m][1][reg] + acc1[m][2][reg] +
                 acc1[m][3][reg];
      float p2 = acc1[m][0][reg] * acc1[m][0][reg] +
                 acc1[m][1][reg] * acc1[m][1][reg] +
                 acc1[m][2][reg] * acc1[m][2][reg] +
                 acc1[m][3][reg] * acc1[m][3][reg];
#pragma unroll
      for (int msk = 1; msk < 16; msk <<= 1) {
        p1 += __shfl_xor(p1, msk, 64);
        p2 += __shfl_xor(p2, msk, 64);
      }
      if (s == 0) {
        const int row = wm * 64 + m * 16 + g * 4 + reg;
        *(float2*)&gnbuf[wn][row][0] = make_float2(p1, p2);
      }
    }
  }
  __syncthreads();  // B2: gnbuf ready; all GEMM1 LDS reads complete

  // ---- normalize + relu -> Ybuf (Y, swizzled) ----
  {
    float gcl[4], bcl[4];
#pragma unroll
    for (int n = 0; n < 4; ++n) {
      gcl[n] = gc1[wn * 64 + n * 16 + s];
      bcl[n] = bc1[wn * 64 + n * 16 + s];
    }
#pragma unroll
    for (int m = 0; m < 4; ++m) {
#pragma unroll
      for (int reg = 0; reg < 4; ++reg) {
        const int row = wm * 64 + m * 16 + g * 4 + reg;
        float2 q0 = *(const float2*)&gnbuf[0][row][0];
        float2 q1 = *(const float2*)&gnbuf[1][row][0];
        const float mean = (q0.x + q1.x) * (1.f / 128.f);
        const float var = (q0.y + q1.y) * (1.f / 128.f) - mean * mean;
        const float rstd = rsqrtf(var + EPSV);
#pragma unroll
        for (int n = 0; n < 4; ++n) {
          float y = fmaxf((acc1[m][n][reg] - mean) * rstd * gcl[n] + bcl[n], 0.f);
          Ybuf[yidx(row, wn * 64 + n * 16 + s)] = (ushort)cvtpk(y, y);
        }
      }
    }
  }
  __syncthreads();  // B3: Y ready

  // ---- GEMM2: K=128 (W chunks 8..11), A = Ybuf ----
  f32x4 acc2[4][4];
#pragma unroll
  for (int m = 0; m < 4; ++m)
#pragma unroll
    for (int n = 0; n < 4; ++n) acc2[m][n] = (f32x4){0.f, 0.f, 0.f, 0.f};

  for (int kc = 0; kc < 4; ++kc) {
    const int c = 8 + kc;
    const int nb = c & 1;
    if (c < 11) stage(c + 1, nb ^ 1);
    bf16x8 a[4];
#pragma unroll
    for (int m = 0; m < 4; ++m)
      a[m] = *(const bf16x8*)
          &Ybuf[yidx(wm * 64 + m * 16 + s, kc * 32 + g * 8)];
#pragma unroll
    for (int n = 0; n < 4; ++n) {
      bf16x8 b = *(const bf16x8*)
          &Wbuf[nb][(g * 128 + wn * 64 + n * 16 + s) * 8];
#pragma unroll
      for (int m = 0; m < 4; ++m)
        acc2[m][n] =
            __builtin_amdgcn_mfma_f32_16x16x32_bf16(a[m], b, acc2[m][n], 0, 0, 0);
    }
    if (kc < 3) __syncthreads();
  }

  // ---- scatter-add ----
#pragma unroll
  for (int m = 0; m < 4; ++m) {
#pragma unroll
    for (int reg = 0; reg < 4; ++reg) {
      const int rl = wm * 64 + m * 16 + g * 4 + reg;
      if (e0 + rl < E) {
        const int w = wl[rl];
        float* base = acc + (size_t)w * D + wn * 64 + s;
#pragma unroll
        for (int n = 0; n < 4; ++n)
          unsafeAtomicAdd(base + n * 16, acc2[m][n][reg]);
      }
    }
  }
}

// ---------------------------------------------------------------------------
__device__ __forceinline__ void reduce16(float& a, float& b) {
#pragma unroll
  for (int w = 1; w < 16; w <<= 1) {
    a += __shfl_xor(a, w, 64);
    b += __shfl_xor(b, w, 64);
  }
}

// ---------------------------------------------------------------------------
// k_input: 64 rows/block, 4 rows/thread.
__global__ __launch_bounds__(256, 2) void k_input(
    const float* __restrict__ tfeat, const float* __restrict__ Wi,
    float* __restrict__ acc, int N) {
  __shared__ float Wbuf[64][132];
  __shared__ float xt[64][132];
  const int t = threadIdx.x;
  const int r = t >> 4, s = t & 15, j0 = s * 8;
  const int row0 = blockIdx.x * 64;

  for (int idx = t; idx < 64 * 32; idx += 256) {
    int rr = idx >> 5, c4 = idx & 31;
    int grow = row0 + rr;
    float4 v = make_float4(0.f, 0.f, 0.f, 0.f);
    if (grow < N) v = *(const float4*)(tfeat + (size_t)grow * D + c4 * 4);
    *(float4*)&xt[rr][c4 * 4] = v;
  }

  float a[4][8] = {};
  for (int kc = 0; kc < 2; ++kc) {
    __syncthreads();
    for (int idx = t; idx < 64 * 32; idx += 256) {
      int kk = idx >> 5, c4 = idx & 31;
      *(float4*)&Wbuf[kk][c4 * 4] =
          *(const float4*)(Wi + (size_t)(kc * 64 + kk) * D + c4 * 4);
    }
    __syncthreads();
#pragma unroll 4
    for (int kk = 0; kk < 64; ++kk) {
      float4 w0 = *(const float4*)&Wbuf[kk][j0];
      float4 w1 = *(const float4*)&Wbuf[kk][j0 + 4];
#pragma unroll
      for (int i = 0; i < 4; ++i) {
        float xv = xt[r + 16 * i][kc * 64 + kk];
        a[i][0] += xv * w0.x; a[i][1] += xv * w0.y;
        a[i][2] += xv * w0.z; a[i][3] += xv * w0.w;
        a[i][4] += xv * w1.x; a[i][5] += xv * w1.y;
        a[i][6] += xv * w1.z; a[i][7] += xv * w1.w;
      }
    }
  }
#pragma unroll
  for (int i = 0; i < 4; ++i) {
    int row = row0 + r + 16 * i;
    if (row < N) {
      *(float4*)(acc + (size_t)row * D + j0) =
          make_float4(a[i][0], a[i][1], a[i][2], a[i][3]);
      *(float4*)(acc + (size_t)row * D + j0 + 4) =
          make_float4(a[i][4], a[i][5], a[i][6], a[i][7]);
    }
  }
}

// ---------------------------------------------------------------------------
// k_node: 64 rows/block, 4 rows/thread; xt reused between stages.
__global__ __launch_bounds__(256, 2) void k_node(
    const float* __restrict__ tfeat,
    const float* __restrict__ gn, const float* __restrict__ bn,
    const float* __restrict__ Wm1, const float* __restrict__ gm1,
    const float* __restrict__ bm1,
    const float* __restrict__ Wm2, const float* __restrict__ gm2,
    const float* __restrict__ bm2,
    float* __restrict__ acc, int N) {
  __shared__ float Wbuf[64][132];
  __shared__ float xt[64][132];
  const int t = threadIdx.x;
  const int r = t >> 4, s = t & 15, j0 = s * 8;
  const int row0 = blockIdx.x * 64;

  auto stageW = [&](const float* W, int kc) {
    for (int idx = t; idx < 64 * 32; idx += 256) {
      int kk = idx >> 5, c4 = idx & 31;
      *(float4*)&Wbuf[kk][c4 * 4] =
          *(const float4*)(W + (size_t)(kc * 64 + kk) * D + c4 * 4);
    }
  };
  auto gemm = [&](float (&a)[4][8], int kc) {
#pragma unroll 4
    for (int kk = 0; kk < 64; ++kk) {
      float4 w0 = *(const float4*)&Wbuf[kk][j0];
      float4 w1 = *(const float4*)&Wbuf[kk][j0 + 4];
#pragma unroll
      for (int i = 0; i < 4; ++i) {
        float xv = xt[r + 16 * i][kc * 64 + kk];
        a[i][0] += xv * w0.x; a[i][1] += xv * w0.y;
        a[i][2] += xv * w0.z; a[i][3] += xv * w0.w;
        a[i][4] += xv * w1.x; a[i][5] += xv * w1.y;
        a[i][6] += xv * w1.z; a[i][7] += xv * w1.w;
      }
    }
  };

  {
    float gv[8], bv[8];
#pragma unroll
    for (int m = 0; m < 8; ++m) { gv[m] = gn[j0 + m]; bv[m] = bn[j0 + m]; }
#pragma unroll
    for (int i = 0; i < 4; ++i) {
      int row = row0 + r + 16 * i;
      float v[8] = {};
      if (row < N) {
        float4 v0 = *(const float4*)(acc + (size_t)row * D + j0);
        float4 v1 = *(const float4*)(acc + (size_t)row * D + j0 + 4);
        v[0] = v0.x; v[1] = v0.y; v[2] = v0.z; v[3] = v0.w;
        v[4] = v1.x; v[5] = v1.y; v[6] = v1.z; v[7] = v1.w;
      }
      float s1 = 0.f, s2 = 0.f;
#pragma unroll
      for (int m = 0; m < 8; ++m) { s1 += v[m]; s2 += v[m] * v[m]; }
      reduce16(s1, s2);
      float mean = s1 * (1.f / 128.f);
      float var = s2 * (1.f / 128.f) - mean * mean;
      float rstd = rsqrtf(var + EPSV);
#pragma unroll
      for (int m = 0; m < 8; ++m)
        xt[r + 16 * i][j0 + m] = fmaxf((v[m] - mean) * rstd * gv[m] + bv[m], 0.f);
    }
  }

  float a[4][8] = {};
  for (int kc = 0; kc < 2; ++kc) {
    __syncthreads();
    stageW(Wm1, kc);
    __syncthreads();
    gemm(a, kc);
  }
  __syncthreads();
  {
    float gv[8], bv[8];
#pragma unroll
    for (int m = 0; m < 8; ++m) { gv[m] = gm1[j0 + m]; bv[m] = bm1[j0 + m]; }
#pragma unroll
    for (int i = 0; i < 4; ++i) {
      float s1 = 0.f, s2 = 0.f;
#pragma unroll
      for (int m = 0; m < 8; ++m) { s1 += a[i][m]; s2 += a[i][m] * a[i][m]; }
      reduce16(s1, s2);
      float mean = s1 * (1.f / 128.f);
      float var = s2 * (1.f / 128.f) - mean * mean;
      float rstd = rsqrtf(var + EPSV);
#pragma unroll
      for (int m = 0; m < 8; ++m)
        xt[r + 16 * i][j0 + m] =
            fmaxf((a[i][m] - mean) * rstd * gv[m] + bv[m], 0.f);
    }
  }

  float a2[4][8] = {};
  for (int kc = 0; kc < 2; ++kc) {
    __syncthreads();
    stageW(Wm2, kc);
    __syncthreads();
    gemm(a2, kc);
  }
  {
    float gv[8], bv[8];
#pragma unroll
    for (int m = 0; m < 8; ++m) { gv[m] = gm2[j0 + m]; bv[m] = bm2[j0 + m]; }
#pragma unroll
    for (int i = 0; i < 4; ++i) {
      int row = row0 + r + 16 * i;
      float s1 = 0.f, s2 = 0.f;
#pragma unroll
      for (int m = 0; m < 8; ++m) { s1 += a2[i][m]; s2 += a2[i][m] * a2[i][m]; }
      reduce16(s1, s2);
      float mean = s1 * (1.f / 128.f);
      float var = s2 * (1.f / 128.f) - mean * mean;
      float rstd = rsqrtf(var + EPSV);
      if (row < N) {
        float o[8];
#pragma unroll
        for (int m = 0; m < 8; ++m) {
          float x = (a2[i][m] - mean) * rstd * gv[m] + bv[m];
          o[m] = fmaxf(x + tfeat[(size_t)row * D + j0 + m], 0.f);
        }
        *(float4*)(acc + (size_t)row * D + j0) =
            make_float4(o[0], o[1], o[2], o[3]);
        *(float4*)(acc + (size_t)row * D + j0 + 4) =
            make_float4(o[4], o[5], o[6], o[7]);
      }
    }
  }
}

// ---------------------------------------------------------------------------
extern "C" void kernel_launch(void* const* d_in, const int* in_sizes, int n_in,
                              void* d_out, int out_size, void* d_ws,
                              size_t ws_size, hipStream_t stream) {
  const float* cfeat = (const float*)d_in[0];
  const float* tfeat = (const float*)d_in[1];
  const float* cpose = (const float*)d_in[2];
  const float* tpose = (const float*)d_in[3];
  const float* Wi    = (const float*)d_in[4];
  const float* Wrp   = (const float*)d_in[5];
  const float* brp   = (const float*)d_in[6];
  const float* Wc1   = (const float*)d_in[7];
  const float* gc1   = (const float*)d_in[8];
  const float* bc1   = (const float*)d_in[9];
  const float* Wc2   = (const float*)d_in[10];
  const float* gn    = (const float*)d_in[11];
  const float* bn    = (const float*)d_in[12];
  const float* Wm1   = (const float*)d_in[13];
  const float* gm1   = (const float*)d_in[14];
  const float* bm1   = (const float*)d_in[15];
  const float* Wm2   = (const float*)d_in[16];
  const float* gm2   = (const float*)d_in[17];
  const float* bm2   = (const float*)d_in[18];
  const int* hi      = (const int*)d_in[19];
  const int* wi      = (const int*)d_in[20];

  const int N = in_sizes[1] / D;   // 40000 targets
  const int E = in_sizes[19];      // 640000 edges
  float* out = (float*)d_out;      // f32 accumulator == output

  ushort* WT1 = (ushort*)d_ws;     // 128x256 bf16 (Wc1^T)
  ushort* WT2 = WT1 + 128 * 256;   // 128x128 bf16 (Wc2^T)

  const int nbN = (N + 63) / 64;
  const int nbE = (E + 127) / 128;

  k_cvt<<<192, 256, 0, stream>>>(Wc1, Wc2, WT1, WT2);
  k_input<<<nbN, 256, 0, stream>>>(tfeat, Wi, out, N);
  k_edge<<<nbE, 256, 0, stream>>>(cfeat, cpose, tpose, Wrp, brp, gc1, bc1,
                                  WT1, WT2, hi, wi, out, E);
  k_node<<<nbN, 256, 0, stream>>>(tfeat, gn, bn, Wm1, gm1, bm1, Wm2, gm2, bm2,
                                  out, N);
}